// Round 4
// baseline (875.754 us; speedup 1.0000x reference)
//
#include <hip/hip_runtime.h>

#define NN 50000
#define MP 50048   // 391 * 128
#define DD 512
#define EE 800000

typedef unsigned short u16;
typedef __attribute__((ext_vector_type(4))) float f32x4;
typedef __attribute__((ext_vector_type(8))) __bf16 bf16x8;
typedef __attribute__((ext_vector_type(8))) short s16x8;
typedef __attribute__((ext_vector_type(4))) short s16x4;

typedef __attribute__((address_space(1))) const void GVoid;
typedef __attribute__((address_space(3))) void LVoid;

__device__ __forceinline__ u16 f2bf(float f) {
  union { float f; unsigned u; } x; x.f = f;
  unsigned r = x.u + 0x7fffu + ((x.u >> 16) & 1u);   // RTNE
  return (u16)(r >> 16);
}
__device__ __forceinline__ float bf2f(u16 b) {
  union { unsigned u; float f; } x; x.u = ((unsigned)b) << 16;
  return x.f;
}

// ---------------- graph preprocessing ----------------
// Self-loops are materialized as real CSR edges: cnt starts at 1, scatter's
// last NN threads append (i -> i, dinv[i]^2).

__global__ __launch_bounds__(256) void init_cnt_k(int* cnt) {
  int i = blockIdx.x * 256 + threadIdx.x;
  if (i < NN) cnt[i] = 1;                      // self-loop pre-counted
}

__global__ __launch_bounds__(256) void count_k(const int* __restrict__ dst, int* __restrict__ cnt) {
  int e = blockIdx.x * 256 + threadIdx.x;
  if (e < EE) atomicAdd(&cnt[dst[e]], 1);
}

__global__ __launch_bounds__(256) void dinv_k(const int* __restrict__ cnt, float* __restrict__ dinv) {
  int i = blockIdx.x * 256 + threadIdx.x;
  if (i < NN) dinv[i] = rsqrtf((float)cnt[i]); // cnt already includes self-loop
}

__global__ __launch_bounds__(1024) void scan_k(const int* __restrict__ cnt, int* __restrict__ rowp,
                                               int* __restrict__ cursor) {
  __shared__ int sums[1024];
  const int t = threadIdx.x;
  const int chunk = (NN + 1023) / 1024;      // 49
  const int beg = t * chunk;
  const int end = (beg + chunk < NN) ? (beg + chunk) : NN;
  int s = 0;
  for (int i = beg; i < end; ++i) s += cnt[i];
  sums[t] = s;
  __syncthreads();
  for (int off = 1; off < 1024; off <<= 1) {   // inclusive Hillis-Steele
    int v = sums[t];
    int u = (t >= off) ? sums[t - off] : 0;
    __syncthreads();
    sums[t] = v + u;
    __syncthreads();
  }
  int run = (t == 0) ? 0 : sums[t - 1];
  for (int i = beg; i < end; ++i) { rowp[i] = run; cursor[i] = run; run += cnt[i]; }
  if (t == 1023) rowp[NN] = run;               // chunks past NN are empty -> run == total
}

// csr entry: .x = src node, .y = weight bits
__global__ __launch_bounds__(256) void scatter_k(const int* __restrict__ src, const int* __restrict__ dst,
                                                 const float* __restrict__ dinv, int* __restrict__ cursor,
                                                 int2* __restrict__ csr) {
  int e = blockIdx.x * 256 + threadIdx.x;
  if (e < EE) {
    int d = dst[e], s = src[e];
    int pos = atomicAdd(&cursor[d], 1);
    csr[pos] = make_int2(s, __float_as_int(dinv[s] * dinv[d]));
  } else if (e < EE + NN) {
    int i = e - EE;                            // self-loop edge
    int pos = atomicAdd(&cursor[i], 1);
    float di = dinv[i];
    csr[pos] = make_int2(i, __float_as_int(di * di));
  }
}

// ---------------- dtype conversion ----------------

__global__ __launch_bounds__(256) void convert_x_k(const float* __restrict__ x, u16* __restrict__ xb) {
  size_t i = ((size_t)blockIdx.x * 256 + threadIdx.x) * 4;
  if (i >= (size_t)MP * DD) return;
  s16x4 v;
  if (i < (size_t)NN * DD) {
    f32x4 f = *(const f32x4*)(x + i);
    v = (s16x4){ (short)f2bf(f.x), (short)f2bf(f.y), (short)f2bf(f.z), (short)f2bf(f.w) };
  } else {
    v = (s16x4){ 0, 0, 0, 0 };                 // zero pad rows (M -> MP); never overwritten later
  }
  *(s16x4*)(xb + i) = v;
}

__global__ __launch_bounds__(256) void convert_wt_k(const float* __restrict__ W, u16* __restrict__ WT, int ncols) {
  int idx = blockIdx.x * 256 + threadIdx.x;    // over ncols*512, WT is [ncols][512] = B^T
  if (idx >= 512 * ncols) return;
  int n = idx >> 9, k = idx & 511;
  WT[idx] = f2bf(W[(size_t)k * ncols + n]);
}

// ---------------- bf16 MFMA GEMM (m97 structure + T1 bijective XCD swizzle) ----------------

template<int OUT_BF16>
__global__ __launch_bounds__(256) void gemm_k(const u16* __restrict__ A, const u16* __restrict__ BT,
                                              void* __restrict__ Cv, const float* __restrict__ bias,
                                              int M, int N) {
  // --- block -> tile (bijective XCD chunking; nwg%8 != 0 safe) ---
  const int nwg = (int)gridDim.x;
  const int id = (int)blockIdx.x;
  const int xcd = id & 7;
  const int idx = id >> 3;
  const int q = nwg >> 3, r = nwg & 7;
  const int tile = (xcd < r ? xcd * (q + 1) : r * (q + 1) + (xcd - r) * q) + idx;
  const int ntn = N >> 7;
  const int bm = tile / ntn;                   // consecutive tiles share bm -> A-panel stays in this XCD's L2
  const int bn = tile % ntn;

  __shared__ u16 As[128 * 32];
  __shared__ u16 Bs[128 * 32];
  const int t = threadIdx.x;
  const int lane = t & 63;
  const int wc = (t >> 6) & 1;
  const int wr = (t >> 7) & 1;
  f32x4 acc[4][4] = {};
  const int r0 = t >> 2;                        // staging row 0..63
  const int kc = (t & 3) * 8;                   // staging k-col
  const u16* Ab = A + (size_t)bm * 128 * DD + (size_t)r0 * DD + kc;
  const u16* Bb = BT + (size_t)bn * 128 * DD + (size_t)r0 * DD + kc;

  for (int kt = 0; kt < DD; kt += 32) {
    __builtin_amdgcn_global_load_lds((GVoid*)(Ab + kt),           (LVoid*)(&As[t * 8]),        16, 0, 0);
    __builtin_amdgcn_global_load_lds((GVoid*)(Ab + 64 * DD + kt), (LVoid*)(&As[2048 + t * 8]), 16, 0, 0);
    __builtin_amdgcn_global_load_lds((GVoid*)(Bb + kt),           (LVoid*)(&Bs[t * 8]),        16, 0, 0);
    __builtin_amdgcn_global_load_lds((GVoid*)(Bb + 64 * DD + kt), (LVoid*)(&Bs[2048 + t * 8]), 16, 0, 0);
    __syncthreads();                            // compiler drains vmcnt before barrier
    bf16x8 af[4], bv[4];
    #pragma unroll
    for (int m = 0; m < 4; ++m)
      af[m] = *(const bf16x8*)&As[(wr * 64 + m * 16 + (lane & 15)) * 32 + (lane >> 4) * 8];
    #pragma unroll
    for (int n = 0; n < 4; ++n)
      bv[n] = *(const bf16x8*)&Bs[(wc * 64 + n * 16 + (lane & 15)) * 32 + (lane >> 4) * 8];
    #pragma unroll
    for (int m = 0; m < 4; ++m) {
      #pragma unroll
      for (int n = 0; n < 4; ++n)
        acc[m][n] = __builtin_amdgcn_mfma_f32_16x16x32_bf16(af[m], bv[n], acc[m][n], 0, 0, 0);
    }
    __syncthreads();                            // protect LDS before next stage
  }

  // C layout (m89-verified): col = lane&15, row = (lane>>4)*4 + reg
  const int rb = bm * 128 + wr * 64 + ((lane >> 4) * 4);
  const int cb = bn * 128 + wc * 64 + (lane & 15);
  #pragma unroll
  for (int m = 0; m < 4; ++m) {
    #pragma unroll
    for (int rr = 0; rr < 4; ++rr) {
      const int row = rb + m * 16 + rr;
      if (row < M) {
        #pragma unroll
        for (int n = 0; n < 4; ++n) {
          const int col = cb + n * 16;
          float v = acc[m][n][rr];
          if (bias) v += bias[col];
          if (OUT_BF16) ((u16*)Cv)[(size_t)row * N + col] = f2bf(v);
          else          ((float*)Cv)[(size_t)row * N + col] = v;
        }
      }
    }
  }
}

// ---------------- CSR aggregation: XCD-pinned dim slices ----------------
// 8 slices of 64 dims; slice s runs only on XCD s (blockIdx%8 round-robin, m09).
// Per-XCD H working set: 50K rows x 128B = 6.4 MB ~ L2-sized, ~17x reuse/row
// -> L2 captures the gather reuse that a 51 MB working set could not.
// Lane d owns dim slice*64+d: scalar f32 acc, no cross-lane reduction; a wave's
// 64 x u16 loads for one edge coalesce to a single 128B line.

__global__ __launch_bounds__(256) void aggregate_k(const u16* __restrict__ H, const int* __restrict__ rowp,
                                                   const int2* __restrict__ csr,
                                                   const float* __restrict__ bias,
                                                   u16* __restrict__ out) {
  const int slice = blockIdx.x & 7;             // XCD-pinned dim slice
  const int grp = blockIdx.x >> 3;              // node group 0..12499
  const int wid = threadIdx.x >> 6;
  const int lane = threadIdx.x & 63;
  const int node = grp * 4 + wid;
  const int d = slice * 64 + lane;
  const int beg = rowp[node];
  const int end = rowp[node + 1];
  const u16* Hd = H + d;
  float acc = 0.f;
  int e = beg;
  for (; e + 4 <= end; e += 4) {
    const int2 c0 = csr[e], c1 = csr[e + 1], c2 = csr[e + 2], c3 = csr[e + 3];
    const float v0 = bf2f(Hd[(size_t)c0.x * DD]);
    const float v1 = bf2f(Hd[(size_t)c1.x * DD]);
    const float v2 = bf2f(Hd[(size_t)c2.x * DD]);
    const float v3 = bf2f(Hd[(size_t)c3.x * DD]);
    acc += v0 * __int_as_float(c0.y);
    acc += v1 * __int_as_float(c1.y);
    acc += v2 * __int_as_float(c2.y);
    acc += v3 * __int_as_float(c3.y);
  }
  for (; e < end; ++e) {
    const int2 c = csr[e];
    acc += bf2f(Hd[(size_t)c.x * DD]) * __int_as_float(c.y);
  }
  const float r = fmaxf(acc + bias[d], 0.f);    // bias + relu
  out[(size_t)node * DD + d] = f2bf(r);
}

// ---------------- launch ----------------

extern "C" void kernel_launch(void* const* d_in, const int* in_sizes, int n_in,
                              void* d_out, int out_size, void* d_ws, size_t ws_size,
                              hipStream_t stream) {
  const float* x    = (const float*)d_in[0];
  const int*   ei   = (const int*)d_in[1];
  const float* W1   = (const float*)d_in[2];
  const float* b1   = (const float*)d_in[3];
  const float* W2   = (const float*)d_in[4];
  const float* b2   = (const float*)d_in[5];
  const float* Wout = (const float*)d_in[6];
  const float* bout = (const float*)d_in[7];
  float* out = (float*)d_out;
  (void)in_sizes; (void)n_in; (void)out_size; (void)ws_size;

  char* ws = (char*)d_ws;
  size_t off = 0;
  auto alloc = [&](size_t bytes) -> char* {
    char* p = ws + off;
    off = (off + bytes + 255) & ~(size_t)255;
    return p;
  };
  u16*   xb   = (u16*)alloc((size_t)MP * DD * 2);   // activations bf16, padded rows
  u16*   H    = (u16*)alloc((size_t)NN * DD * 2);   // GEMM output bf16
  u16*   W1T  = (u16*)alloc(512 * 512 * 2);
  u16*   W2T  = (u16*)alloc(512 * 512 * 2);
  u16*   WoT  = (u16*)alloc(256 * 512 * 2);
  int*   cnt  = (int*)alloc(NN * 4);
  float* dinv = (float*)alloc(NN * 4);
  int*   rowp = (int*)alloc((NN + 1) * 4);
  int*   cur  = (int*)alloc(NN * 4);
  int2*  csr  = (int2*)alloc((size_t)(EE + NN) * 8);

  const int* srcp = ei;        // edge_index[0]
  const int* dstp = ei + EE;   // edge_index[1]

  init_cnt_k<<<(NN + 255) / 256, 256, 0, stream>>>(cnt);
  count_k<<<(EE + 255) / 256, 256, 0, stream>>>(dstp, cnt);
  dinv_k<<<(NN + 255) / 256, 256, 0, stream>>>(cnt, dinv);
  scan_k<<<1, 1024, 0, stream>>>(cnt, rowp, cur);
  scatter_k<<<(EE + NN + 255) / 256, 256, 0, stream>>>(srcp, dstp, dinv, cur, csr);
  convert_x_k<<<(int)(((size_t)MP * DD / 4 + 255) / 256), 256, 0, stream>>>(x, xb);
  convert_wt_k<<<(512 * 512 + 255) / 256, 256, 0, stream>>>(W1, W1T, 512);
  convert_wt_k<<<(512 * 512 + 255) / 256, 256, 0, stream>>>(W2, W2T, 512);
  convert_wt_k<<<(512 * 256 + 255) / 256, 256, 0, stream>>>(Wout, WoT, 256);

  const int agg_grid = (NN / 4) * 8;            // 12500 node-groups x 8 XCD slices

  // layer 1: H = xb @ W1 ; xb = relu(agg(H) + b1)
  gemm_k<1><<<(MP / 128) * (512 / 128), 256, 0, stream>>>(xb, W1T, (void*)H, nullptr, NN, 512);
  aggregate_k<<<agg_grid, 256, 0, stream>>>(H, rowp, csr, b1, xb);
  // layer 2
  gemm_k<1><<<(MP / 128) * (512 / 128), 256, 0, stream>>>(xb, W2T, (void*)H, nullptr, NN, 512);
  aggregate_k<<<agg_grid, 256, 0, stream>>>(H, rowp, csr, b2, xb);
  // output layer: out = xb @ Wout + bout (f32, no relu, no aggregation)
  gemm_k<0><<<(MP / 128) * (256 / 128), 256, 0, stream>>>(xb, WoT, (void*)out, bout, NN, 256);
}

// Round 5
// 500.143 us; speedup vs baseline: 1.7510x; 1.7510x over previous
//
#include <hip/hip_runtime.h>

#define NN 50000
#define MP 50048   // 391 * 128
#define DD 512
#define EE 800000
#define NSCAN 196  // ceil(NN/256)

typedef unsigned short u16;
typedef __attribute__((ext_vector_type(4))) float f32x4;
typedef __attribute__((ext_vector_type(8))) __bf16 bf16x8;
typedef __attribute__((ext_vector_type(8))) short s16x8;
typedef __attribute__((ext_vector_type(4))) short s16x4;

typedef __attribute__((address_space(1))) const void GVoid;
typedef __attribute__((address_space(3))) void LVoid;

__device__ __forceinline__ u16 f2bf(float f) {
  union { float f; unsigned u; } x; x.f = f;
  unsigned r = x.u + 0x7fffu + ((x.u >> 16) & 1u);   // RTNE
  return (u16)(r >> 16);
}
__device__ __forceinline__ float bf2f(u16 b) {
  union { unsigned u; float f; } x; x.u = ((unsigned)b) << 16;
  return x.f;
}

// ---------------- graph preprocessing ----------------
// Self-loops are materialized as real CSR edges: cnt starts at 1, scatter's
// last NN threads append (i -> i, dinv[i]^2).

__global__ __launch_bounds__(256) void init_cnt_k(int* cnt) {
  int i = blockIdx.x * 256 + threadIdx.x;
  if (i < NN) cnt[i] = 1;                      // self-loop pre-counted
}

__global__ __launch_bounds__(256) void count_k(const int* __restrict__ dst, int* __restrict__ cnt) {
  int e = blockIdx.x * 256 + threadIdx.x;
  if (e < EE) atomicAdd(&cnt[dst[e]], 1);
}

__global__ __launch_bounds__(256) void dinv_k(const int* __restrict__ cnt, float* __restrict__ dinv) {
  int i = blockIdx.x * 256 + threadIdx.x;
  if (i < NN) dinv[i] = rsqrtf((float)cnt[i]); // cnt already includes self-loop
}

// --- 3-stage parallel exclusive scan over cnt[NN] (replaces serial 1-block scan) ---

__global__ __launch_bounds__(256) void scan1_k(const int* __restrict__ cnt, int* __restrict__ bsum) {
  __shared__ int s[256];
  const int t = threadIdx.x;
  const int i = blockIdx.x * 256 + t;
  s[t] = (i < NN) ? cnt[i] : 0;
  __syncthreads();
  for (int off = 128; off > 0; off >>= 1) {
    if (t < off) s[t] += s[t + off];
    __syncthreads();
  }
  if (t == 0) bsum[blockIdx.x] = s[0];
}

__global__ __launch_bounds__(256) void scan2_k(const int* __restrict__ bsum, int* __restrict__ boff) {
  __shared__ int s[256];
  const int t = threadIdx.x;
  const int v = (t < NSCAN) ? bsum[t] : 0;
  s[t] = v;
  __syncthreads();
  for (int off = 1; off < 256; off <<= 1) {    // inclusive Hillis-Steele
    int a = s[t];
    int b = (t >= off) ? s[t - off] : 0;
    __syncthreads();
    s[t] = a + b;
    __syncthreads();
  }
  if (t < NSCAN) boff[t] = s[t] - v;           // exclusive
}

__global__ __launch_bounds__(256) void scan3_k(const int* __restrict__ cnt, const int* __restrict__ boff,
                                               int* __restrict__ rowp, int* __restrict__ cursor) {
  __shared__ int s[256];
  const int t = threadIdx.x;
  const int i = blockIdx.x * 256 + t;
  const int v = (i < NN) ? cnt[i] : 0;
  s[t] = v;
  __syncthreads();
  for (int off = 1; off < 256; off <<= 1) {    // inclusive
    int a = s[t];
    int b = (t >= off) ? s[t - off] : 0;
    __syncthreads();
    s[t] = a + b;
    __syncthreads();
  }
  const int excl = s[t] - v + boff[blockIdx.x];
  if (i < NN) { rowp[i] = excl; cursor[i] = excl; }
  if (i == NN - 1) rowp[NN] = excl + v;        // total = EE + NN
}

// csr entry: .x = src node, .y = weight bits
__global__ __launch_bounds__(256) void scatter_k(const int* __restrict__ src, const int* __restrict__ dst,
                                                 const float* __restrict__ dinv, int* __restrict__ cursor,
                                                 int2* __restrict__ csr) {
  int e = blockIdx.x * 256 + threadIdx.x;
  if (e < EE) {
    int d = dst[e], s = src[e];
    int pos = atomicAdd(&cursor[d], 1);
    csr[pos] = make_int2(s, __float_as_int(dinv[s] * dinv[d]));
  } else if (e < EE + NN) {
    int i = e - EE;                            // self-loop edge
    int pos = atomicAdd(&cursor[i], 1);
    float di = dinv[i];
    csr[pos] = make_int2(i, __float_as_int(di * di));
  }
}

// ---------------- dtype conversion ----------------

__global__ __launch_bounds__(256) void convert_x_k(const float* __restrict__ x, u16* __restrict__ xb) {
  size_t i = ((size_t)blockIdx.x * 256 + threadIdx.x) * 4;
  if (i >= (size_t)MP * DD) return;
  s16x4 v;
  if (i < (size_t)NN * DD) {
    f32x4 f = *(const f32x4*)(x + i);
    v = (s16x4){ (short)f2bf(f.x), (short)f2bf(f.y), (short)f2bf(f.z), (short)f2bf(f.w) };
  } else {
    v = (s16x4){ 0, 0, 0, 0 };                 // zero pad rows (M -> MP); never overwritten later
  }
  *(s16x4*)(xb + i) = v;
}

__global__ __launch_bounds__(256) void convert_wt_k(const float* __restrict__ W, u16* __restrict__ WT, int ncols) {
  int idx = blockIdx.x * 256 + threadIdx.x;    // over ncols*512, WT is [ncols][512] = B^T
  if (idx >= 512 * ncols) return;
  int n = idx >> 9, k = idx & 511;
  WT[idx] = f2bf(W[(size_t)k * ncols + n]);
}

// ---------------- bf16 MFMA GEMM: m97 structure + 2-phase double buffer ----------------
// T3 "minimum 2-phase": stage tile t+1 into buf^1 BEFORE computing tile t, single
// barrier per step -> global-load latency (~600cy) hides under ds_read+MFMA.
// LDS 32KB -> 5 blocks/CU. K=512 -> 16 steps.

template<int OUT_BF16>
__global__ __launch_bounds__(256) void gemm_k(const u16* __restrict__ A, const u16* __restrict__ BT,
                                              void* __restrict__ Cv, const float* __restrict__ bias,
                                              int M, int N) {
  // bijective XCD chunking (bn-fastest => consecutive tiles share bm / A-panel)
  const int nwg = (int)gridDim.x;
  const int id = (int)blockIdx.x;
  const int xcd = id & 7;
  const int idx = id >> 3;
  const int q = nwg >> 3, r = nwg & 7;
  const int tile = (xcd < r ? xcd * (q + 1) : r * (q + 1) + (xcd - r) * q) + idx;
  const int ntn = N >> 7;
  const int bm = tile / ntn;
  const int bn = tile % ntn;

  __shared__ u16 As[2][128 * 32];
  __shared__ u16 Bs[2][128 * 32];
  const int t = threadIdx.x;
  const int lane = t & 63;
  const int wc = (t >> 6) & 1;
  const int wr = (t >> 7) & 1;
  f32x4 acc[4][4] = {};
  const int r0 = t >> 2;                        // staging row 0..63
  const int kc = (t & 3) * 8;                   // staging k-col
  const u16* Ab = A + (size_t)bm * 128 * DD + (size_t)r0 * DD + kc;
  const u16* Bb = BT + (size_t)bn * 128 * DD + (size_t)r0 * DD + kc;

  auto stage = [&](int buf, int kt) {
    __builtin_amdgcn_global_load_lds((GVoid*)(Ab + kt),           (LVoid*)(&As[buf][t * 8]),        16, 0, 0);
    __builtin_amdgcn_global_load_lds((GVoid*)(Ab + 64 * DD + kt), (LVoid*)(&As[buf][2048 + t * 8]), 16, 0, 0);
    __builtin_amdgcn_global_load_lds((GVoid*)(Bb + kt),           (LVoid*)(&Bs[buf][t * 8]),        16, 0, 0);
    __builtin_amdgcn_global_load_lds((GVoid*)(Bb + 64 * DD + kt), (LVoid*)(&Bs[buf][2048 + t * 8]), 16, 0, 0);
  };

  stage(0, 0);
  __syncthreads();                              // vmcnt(0) drain: buf0 ready

  #pragma unroll 2
  for (int step = 0; step < 16; ++step) {
    const int cur = step & 1;
    if (step < 15) stage(cur ^ 1, (step + 1) * 32);   // prefetch next tile
    bf16x8 af[4], bv[4];
    #pragma unroll
    for (int m = 0; m < 4; ++m)
      af[m] = *(const bf16x8*)&As[cur][(wr * 64 + m * 16 + (lane & 15)) * 32 + (lane >> 4) * 8];
    #pragma unroll
    for (int n = 0; n < 4; ++n)
      bv[n] = *(const bf16x8*)&Bs[cur][(wc * 64 + n * 16 + (lane & 15)) * 32 + (lane >> 4) * 8];
    #pragma unroll
    for (int m = 0; m < 4; ++m) {
      #pragma unroll
      for (int n = 0; n < 4; ++n)
        acc[m][n] = __builtin_amdgcn_mfma_f32_16x16x32_bf16(af[m], bv[n], acc[m][n], 0, 0, 0);
    }
    __syncthreads();                            // drains next-tile loads + LDS sync
  }

  // C layout (m89-verified): col = lane&15, row = (lane>>4)*4 + reg
  const int rb = bm * 128 + wr * 64 + ((lane >> 4) * 4);
  const int cb = bn * 128 + wc * 64 + (lane & 15);
  #pragma unroll
  for (int m = 0; m < 4; ++m) {
    #pragma unroll
    for (int rr = 0; rr < 4; ++rr) {
      const int row = rb + m * 16 + rr;
      if (row < M) {
        #pragma unroll
        for (int n = 0; n < 4; ++n) {
          const int col = cb + n * 16;
          float v = acc[m][n][rr];
          if (bias) v += bias[col];
          if (OUT_BF16) ((u16*)Cv)[(size_t)row * N + col] = f2bf(v);
          else          ((float*)Cv)[(size_t)row * N + col] = v;
        }
      }
    }
  }
}

// ---------------- CSR aggregation: R2-exact form (measured 124us, ~87% of the
// 400MB@3.7TB/s compulsory per-XCD L2-fill wall). Wave per node, 8 dims/lane,
// 4-edge-deep unroll. ----------------

__global__ __launch_bounds__(256) void aggregate_k(const u16* __restrict__ H, const int* __restrict__ rowp,
                                                   const int2* __restrict__ csr,
                                                   const float* __restrict__ bias,
                                                   u16* __restrict__ out) {
  const int wid = threadIdx.x >> 6;
  const int lane = threadIdx.x & 63;
  const int node = blockIdx.x * 4 + wid;        // grid = NN/4 exactly
  const int d0 = lane * 8;
  const int beg = rowp[node];
  const int end = rowp[node + 1];
  float acc[8] = {0.f, 0.f, 0.f, 0.f, 0.f, 0.f, 0.f, 0.f};
  int e = beg;
  for (; e + 4 <= end; e += 4) {
    const int2 c0 = csr[e], c1 = csr[e + 1], c2 = csr[e + 2], c3 = csr[e + 3];
    const s16x8 v0 = *(const s16x8*)(H + (size_t)c0.x * DD + d0);
    const s16x8 v1 = *(const s16x8*)(H + (size_t)c1.x * DD + d0);
    const s16x8 v2 = *(const s16x8*)(H + (size_t)c2.x * DD + d0);
    const s16x8 v3 = *(const s16x8*)(H + (size_t)c3.x * DD + d0);
    const float w0 = __int_as_float(c0.y), w1 = __int_as_float(c1.y);
    const float w2 = __int_as_float(c2.y), w3 = __int_as_float(c3.y);
    #pragma unroll
    for (int j = 0; j < 8; ++j) {
      acc[j] += bf2f((u16)v0[j]) * w0;
      acc[j] += bf2f((u16)v1[j]) * w1;
      acc[j] += bf2f((u16)v2[j]) * w2;
      acc[j] += bf2f((u16)v3[j]) * w3;
    }
  }
  for (; e < end; ++e) {
    const int2 c = csr[e];
    const s16x8 v = *(const s16x8*)(H + (size_t)c.x * DD + d0);
    const float w = __int_as_float(c.y);
    #pragma unroll
    for (int j = 0; j < 8; ++j) acc[j] += bf2f((u16)v[j]) * w;
  }
  s16x8 o;
  #pragma unroll
  for (int j = 0; j < 8; ++j) {
    float r = acc[j] + bias[d0 + j];
    r = fmaxf(r, 0.f);                          // relu
    o[j] = (short)f2bf(r);
  }
  *(s16x8*)(out + (size_t)node * DD + d0) = o;
}

// ---------------- launch ----------------

extern "C" void kernel_launch(void* const* d_in, const int* in_sizes, int n_in,
                              void* d_out, int out_size, void* d_ws, size_t ws_size,
                              hipStream_t stream) {
  const float* x    = (const float*)d_in[0];
  const int*   ei   = (const int*)d_in[1];
  const float* W1   = (const float*)d_in[2];
  const float* b1   = (const float*)d_in[3];
  const float* W2   = (const float*)d_in[4];
  const float* b2   = (const float*)d_in[5];
  const float* Wout = (const float*)d_in[6];
  const float* bout = (const float*)d_in[7];
  float* out = (float*)d_out;
  (void)in_sizes; (void)n_in; (void)out_size; (void)ws_size;

  char* ws = (char*)d_ws;
  size_t off = 0;
  auto alloc = [&](size_t bytes) -> char* {
    char* p = ws + off;
    off = (off + bytes + 255) & ~(size_t)255;
    return p;
  };
  u16*   xb   = (u16*)alloc((size_t)MP * DD * 2);   // activations bf16, padded rows
  u16*   H    = (u16*)alloc((size_t)NN * DD * 2);   // GEMM output bf16
  u16*   W1T  = (u16*)alloc(512 * 512 * 2);
  u16*   W2T  = (u16*)alloc(512 * 512 * 2);
  u16*   WoT  = (u16*)alloc(256 * 512 * 2);
  int*   cnt  = (int*)alloc(NN * 4);
  float* dinv = (float*)alloc(NN * 4);
  int*   rowp = (int*)alloc((NN + 1) * 4);
  int*   cur  = (int*)alloc(NN * 4);
  int2*  csr  = (int2*)alloc((size_t)(EE + NN) * 8);
  int*   bsum = (int*)alloc(NSCAN * 4);
  int*   boff = (int*)alloc(NSCAN * 4);

  const int* srcp = ei;        // edge_index[0]
  const int* dstp = ei + EE;   // edge_index[1]

  init_cnt_k<<<(NN + 255) / 256, 256, 0, stream>>>(cnt);
  count_k<<<(EE + 255) / 256, 256, 0, stream>>>(dstp, cnt);
  dinv_k<<<(NN + 255) / 256, 256, 0, stream>>>(cnt, dinv);
  scan1_k<<<NSCAN, 256, 0, stream>>>(cnt, bsum);
  scan2_k<<<1, 256, 0, stream>>>(bsum, boff);
  scan3_k<<<NSCAN, 256, 0, stream>>>(cnt, boff, rowp, cur);
  scatter_k<<<(EE + NN + 255) / 256, 256, 0, stream>>>(srcp, dstp, dinv, cur, csr);
  convert_x_k<<<(int)(((size_t)MP * DD / 4 + 255) / 256), 256, 0, stream>>>(x, xb);
  convert_wt_k<<<(512 * 512 + 255) / 256, 256, 0, stream>>>(W1, W1T, 512);
  convert_wt_k<<<(512 * 512 + 255) / 256, 256, 0, stream>>>(W2, W2T, 512);
  convert_wt_k<<<(512 * 256 + 255) / 256, 256, 0, stream>>>(Wout, WoT, 256);

  // layer 1: H = xb @ W1 ; xb = relu(agg(H) + b1)
  gemm_k<1><<<(MP / 128) * (512 / 128), 256, 0, stream>>>(xb, W1T, (void*)H, nullptr, NN, 512);
  aggregate_k<<<NN / 4, 256, 0, stream>>>(H, rowp, csr, b1, xb);
  // layer 2
  gemm_k<1><<<(MP / 128) * (512 / 128), 256, 0, stream>>>(xb, W2T, (void*)H, nullptr, NN, 512);
  aggregate_k<<<NN / 4, 256, 0, stream>>>(H, rowp, csr, b2, xb);
  // output layer: out = xb @ Wout + bout (f32, no relu, no aggregation)
  gemm_k<0><<<(MP / 128) * (256 / 128), 256, 0, stream>>>(xb, WoT, (void*)out, bout, NN, 256);
}

// Round 6
// 478.611 us; speedup vs baseline: 1.8298x; 1.0450x over previous
//
#include <hip/hip_runtime.h>

#define NN 50000
#define MP 50048   // 391 * 128
#define DD 512
#define EE 800000
#define NSCAN 196  // ceil(NN/256)
#define SCB 3321   // ceil((EE+NN)/256) scatter blocks fused into gemm1
#define G1TILES 1564  // (MP/128)*(512/128)

typedef unsigned short u16;
typedef __attribute__((ext_vector_type(4))) float f32x4;
typedef __attribute__((ext_vector_type(8))) __bf16 bf16x8;
typedef __attribute__((ext_vector_type(8))) short s16x8;

typedef __attribute__((address_space(1))) const void GVoid;
typedef __attribute__((address_space(3))) void LVoid;

__device__ __forceinline__ u16 f2bf(float f) {
  union { float f; unsigned u; } x; x.f = f;
  unsigned r = x.u + 0x7fffu + ((x.u >> 16) & 1u);   // RTNE
  return (u16)(r >> 16);
}
__device__ __forceinline__ float bf2f(u16 b) {
  union { unsigned u; float f; } x; x.u = ((unsigned)b) << 16;
  return x.f;
}

// ---------------- setup: cnt=1 (self-loop) + all 3 weight transposes, one launch ----------------

__global__ __launch_bounds__(256) void setup_k(int* __restrict__ cnt,
                                               const float* __restrict__ W1, u16* __restrict__ W1T,
                                               const float* __restrict__ W2, u16* __restrict__ W2T,
                                               const float* __restrict__ Wo, u16* __restrict__ WoT) {
  const int b = (int)blockIdx.x, t = threadIdx.x;
  if (b < 196) { int i = b * 256 + t; if (i < NN) cnt[i] = 1; return; }
  const float* W; u16* WT; int ncols, idx;
  if (b < 1220)      { W = W1; WT = W1T; ncols = 512; idx = (b - 196) * 256 + t; }
  else if (b < 2244) { W = W2; WT = W2T; ncols = 512; idx = (b - 1220) * 256 + t; }
  else               { W = Wo; WT = WoT; ncols = 256; idx = (b - 2244) * 256 + t; }
  if (idx >= 512 * ncols) return;
  int n = idx >> 9, k = idx & 511;             // WT[ncols][512] = W^T
  WT[idx] = f2bf(W[(size_t)k * ncols + n]);
}

__global__ __launch_bounds__(256) void count_k(const int* __restrict__ dst, int* __restrict__ cnt) {
  int e = blockIdx.x * 256 + threadIdx.x;
  if (e < EE) atomicAdd(&cnt[dst[e]], 1);
}

// --- 3-stage parallel exclusive scan over cnt[NN]; scan3 also emits dinv ---

__global__ __launch_bounds__(256) void scan1_k(const int* __restrict__ cnt, int* __restrict__ bsum) {
  __shared__ int s[256];
  const int t = threadIdx.x;
  const int i = blockIdx.x * 256 + t;
  s[t] = (i < NN) ? cnt[i] : 0;
  __syncthreads();
  for (int off = 128; off > 0; off >>= 1) {
    if (t < off) s[t] += s[t + off];
    __syncthreads();
  }
  if (t == 0) bsum[blockIdx.x] = s[0];
}

__global__ __launch_bounds__(256) void scan2_k(const int* __restrict__ bsum, int* __restrict__ boff) {
  __shared__ int s[256];
  const int t = threadIdx.x;
  const int v = (t < NSCAN) ? bsum[t] : 0;
  s[t] = v;
  __syncthreads();
  for (int off = 1; off < 256; off <<= 1) {    // inclusive Hillis-Steele
    int a = s[t];
    int b = (t >= off) ? s[t - off] : 0;
    __syncthreads();
    s[t] = a + b;
    __syncthreads();
  }
  if (t < NSCAN) boff[t] = s[t] - v;           // exclusive
}

__global__ __launch_bounds__(256) void scan3_k(const int* __restrict__ cnt, const int* __restrict__ boff,
                                               int* __restrict__ rowp, int* __restrict__ cursor,
                                               float* __restrict__ dinv) {
  __shared__ int s[256];
  const int t = threadIdx.x;
  const int i = blockIdx.x * 256 + t;
  const int v = (i < NN) ? cnt[i] : 0;
  s[t] = v;
  __syncthreads();
  for (int off = 1; off < 256; off <<= 1) {    // inclusive
    int a = s[t];
    int b = (t >= off) ? s[t - off] : 0;
    __syncthreads();
    s[t] = a + b;
    __syncthreads();
  }
  const int excl = s[t] - v + boff[blockIdx.x];
  if (i < NN) {
    rowp[i] = excl; cursor[i] = excl;
    dinv[i] = rsqrtf((float)v);                // v includes self-loop
  }
  if (i == NN - 1) rowp[NN] = excl + v;        // total = EE + NN
}

// ---------------- GEMM-1 (f32 A direct, reg-staged) + fused scatter blocks ----------------
// First SCB blocks build CSR (independent of GEMM work, hides ~20us under MFMA);
// remaining G1TILES blocks run the 2-phase GEMM with A read straight from f32 x
// (kills the 153MB convert_x pass). LDS layout/read path identical to bf16 proven one.

__global__ __launch_bounds__(256) void gemm1_k(const float* __restrict__ X, const u16* __restrict__ BT,
                                               u16* __restrict__ C,
                                               const int* __restrict__ src, const int* __restrict__ dst,
                                               const float* __restrict__ dinv, int* __restrict__ cursor,
                                               int2* __restrict__ csr) {
  __shared__ u16 As[2][128 * 32];
  __shared__ u16 Bs[2][128 * 32];
  const int t = threadIdx.x;

  if (blockIdx.x < SCB) {                      // ---- scatter branch ----
    int e = (int)blockIdx.x * 256 + t;
    if (e < EE) {
      int d = dst[e], sn = src[e];
      int pos = atomicAdd(&cursor[d], 1);
      csr[pos] = make_int2(sn, __float_as_int(dinv[sn] * dinv[d]));
    } else if (e < EE + NN) {
      int i = e - EE;                          // self-loop edge
      int pos = atomicAdd(&cursor[i], 1);
      float di = dinv[i];
      csr[pos] = make_int2(i, __float_as_int(di * di));
    }
    return;
  }

  // ---- GEMM branch: bijective XCD chunking over G1TILES ----
  const int g = (int)blockIdx.x - SCB;
  const int xcd = g & 7;
  const int idx = g >> 3;
  const int q = G1TILES >> 3, r = G1TILES & 7;
  const int tile = (xcd < r ? xcd * (q + 1) : r * (q + 1) + (xcd - r) * q) + idx;
  const int bm = tile >> 2;                    // ntn = 4
  const int bn = tile & 3;

  const int lane = t & 63;
  const int wc = (t >> 6) & 1;
  const int wr = (t >> 7) & 1;
  f32x4 acc[4][4] = {};
  const int r0 = t >> 2;                        // staging row 0..63
  const int kc = (t & 3) * 8;                   // staging k-col (elements)
  const int row1 = bm * 128 + 64 + r0;          // only the +64 region can exceed NN
  const float* Xp0 = X + (size_t)(bm * 128 + r0) * DD + kc;
  const float* Xp1 = X + (size_t)(row1 < NN ? row1 : NN - 1) * DD + kc;
  const u16* Bb = BT + (size_t)bn * 128 * DD + (size_t)r0 * DD + kc;

  f32x4 a0, a1, a2, a3;
  auto loadA = [&](int kt) {
    a0 = *(const f32x4*)(Xp0 + kt);
    a1 = *(const f32x4*)(Xp0 + kt + 4);
    a2 = *(const f32x4*)(Xp1 + kt);
    a3 = *(const f32x4*)(Xp1 + kt + 4);
  };
  auto writeA = [&](int buf) {
    bf16x8 w0, w1;
    #pragma unroll
    for (int j = 0; j < 4; ++j) {
      w0[j] = (__bf16)a0[j]; w0[4 + j] = (__bf16)a1[j];
      w1[j] = (__bf16)a2[j]; w1[4 + j] = (__bf16)a3[j];
    }
    *(bf16x8*)&As[buf][t * 8] = w0;
    *(bf16x8*)&As[buf][2048 + t * 8] = w1;
  };
  auto stageB = [&](int buf, int kt) {
    __builtin_amdgcn_global_load_lds((GVoid*)(Bb + kt),           (LVoid*)(&Bs[buf][t * 8]),        16, 0, 0);
    __builtin_amdgcn_global_load_lds((GVoid*)(Bb + 64 * DD + kt), (LVoid*)(&Bs[buf][2048 + t * 8]), 16, 0, 0);
  };

  loadA(0);
  stageB(0, 0);
  writeA(0);
  __syncthreads();                              // buf0 ready (A written, B drained)

  #pragma unroll 2
  for (int step = 0; step < 16; ++step) {
    const int cur = step & 1;
    if (step < 15) { loadA((step + 1) * 32); stageB(cur ^ 1, (step + 1) * 32); }
    bf16x8 af[4], bv[4];
    #pragma unroll
    for (int m = 0; m < 4; ++m)
      af[m] = *(const bf16x8*)&As[cur][(wr * 64 + m * 16 + (lane & 15)) * 32 + (lane >> 4) * 8];
    #pragma unroll
    for (int n = 0; n < 4; ++n)
      bv[n] = *(const bf16x8*)&Bs[cur][(wc * 64 + n * 16 + (lane & 15)) * 32 + (lane >> 4) * 8];
    #pragma unroll
    for (int m = 0; m < 4; ++m) {
      #pragma unroll
      for (int n = 0; n < 4; ++n)
        acc[m][n] = __builtin_amdgcn_mfma_f32_16x16x32_bf16(af[m], bv[n], acc[m][n], 0, 0, 0);
    }
    if (step < 15) writeA(cur ^ 1);             // cvt + ds_write after MFMA (loads in flight during MFMA)
    __syncthreads();
  }

  const int rb = bm * 128 + wr * 64 + ((lane >> 4) * 4);
  const int cb = bn * 128 + wc * 64 + (lane & 15);
  #pragma unroll
  for (int m = 0; m < 4; ++m) {
    #pragma unroll
    for (int rr = 0; rr < 4; ++rr) {
      const int row = rb + m * 16 + rr;
      if (row < NN) {
        #pragma unroll
        for (int n = 0; n < 4; ++n)
          C[(size_t)row * 512 + cb + n * 16] = f2bf(acc[m][n][rr]);
      }
    }
  }
}

// ---------------- bf16 MFMA GEMM: m97 structure + 2-phase double buffer (layers 2,3) ----------------

template<int OUT_BF16>
__global__ __launch_bounds__(256) void gemm_k(const u16* __restrict__ A, const u16* __restrict__ BT,
                                              void* __restrict__ Cv, const float* __restrict__ bias,
                                              int M, int N) {
  const int nwg = (int)gridDim.x;
  const int id = (int)blockIdx.x;
  const int xcd = id & 7;
  const int idx = id >> 3;
  const int q = nwg >> 3, r = nwg & 7;
  const int tile = (xcd < r ? xcd * (q + 1) : r * (q + 1) + (xcd - r) * q) + idx;
  const int ntn = N >> 7;
  const int bm = tile / ntn;
  const int bn = tile % ntn;

  __shared__ u16 As[2][128 * 32];
  __shared__ u16 Bs[2][128 * 32];
  const int t = threadIdx.x;
  const int lane = t & 63;
  const int wc = (t >> 6) & 1;
  const int wr = (t >> 7) & 1;
  f32x4 acc[4][4] = {};
  const int r0 = t >> 2;
  const int kc = (t & 3) * 8;
  const u16* Ab = A + (size_t)bm * 128 * DD + (size_t)r0 * DD + kc;
  const u16* Bb = BT + (size_t)bn * 128 * DD + (size_t)r0 * DD + kc;

  auto stage = [&](int buf, int kt) {
    __builtin_amdgcn_global_load_lds((GVoid*)(Ab + kt),           (LVoid*)(&As[buf][t * 8]),        16, 0, 0);
    __builtin_amdgcn_global_load_lds((GVoid*)(Ab + 64 * DD + kt), (LVoid*)(&As[buf][2048 + t * 8]), 16, 0, 0);
    __builtin_amdgcn_global_load_lds((GVoid*)(Bb + kt),           (LVoid*)(&Bs[buf][t * 8]),        16, 0, 0);
    __builtin_amdgcn_global_load_lds((GVoid*)(Bb + 64 * DD + kt), (LVoid*)(&Bs[buf][2048 + t * 8]), 16, 0, 0);
  };

  stage(0, 0);
  __syncthreads();

  #pragma unroll 2
  for (int step = 0; step < 16; ++step) {
    const int cur = step & 1;
    if (step < 15) stage(cur ^ 1, (step + 1) * 32);
    bf16x8 af[4], bv[4];
    #pragma unroll
    for (int m = 0; m < 4; ++m)
      af[m] = *(const bf16x8*)&As[cur][(wr * 64 + m * 16 + (lane & 15)) * 32 + (lane >> 4) * 8];
    #pragma unroll
    for (int n = 0; n < 4; ++n)
      bv[n] = *(const bf16x8*)&Bs[cur][(wc * 64 + n * 16 + (lane & 15)) * 32 + (lane >> 4) * 8];
    #pragma unroll
    for (int m = 0; m < 4; ++m) {
      #pragma unroll
      for (int n = 0; n < 4; ++n)
        acc[m][n] = __builtin_amdgcn_mfma_f32_16x16x32_bf16(af[m], bv[n], acc[m][n], 0, 0, 0);
    }
    __syncthreads();
  }

  const int rb = bm * 128 + wr * 64 + ((lane >> 4) * 4);
  const int cb = bn * 128 + wc * 64 + (lane & 15);
  #pragma unroll
  for (int m = 0; m < 4; ++m) {
    #pragma unroll
    for (int rr = 0; rr < 4; ++rr) {
      const int row = rb + m * 16 + rr;
      if (row < M) {
        #pragma unroll
        for (int n = 0; n < 4; ++n) {
          const int col = cb + n * 16;
          float v = acc[m][n][rr];
          if (bias) v += bias[col];
          if (OUT_BF16) ((u16*)Cv)[(size_t)row * N + col] = f2bf(v);
          else          ((float*)Cv)[(size_t)row * N + col] = v;
        }
      }
    }
  }
}

// ---------------- CSR aggregation (R2-exact: 124us, ~87% of the 400MB@3.7TB/s
// per-XCD compulsory L2-fill wall). Wave per node, 8 dims/lane, 4-deep unroll. ----------------

__global__ __launch_bounds__(256) void aggregate_k(const u16* __restrict__ H, const int* __restrict__ rowp,
                                                   const int2* __restrict__ csr,
                                                   const float* __restrict__ bias,
                                                   u16* __restrict__ out) {
  const int wid = threadIdx.x >> 6;
  const int lane = threadIdx.x & 63;
  const int node = blockIdx.x * 4 + wid;        // grid = NN/4 exactly
  const int d0 = lane * 8;
  const int beg = rowp[node];
  const int end = rowp[node + 1];
  float acc[8] = {0.f, 0.f, 0.f, 0.f, 0.f, 0.f, 0.f, 0.f};
  int e = beg;
  for (; e + 4 <= end; e += 4) {
    const int2 c0 = csr[e], c1 = csr[e + 1], c2 = csr[e + 2], c3 = csr[e + 3];
    const s16x8 v0 = *(const s16x8*)(H + (size_t)c0.x * DD + d0);
    const s16x8 v1 = *(const s16x8*)(H + (size_t)c1.x * DD + d0);
    const s16x8 v2 = *(const s16x8*)(H + (size_t)c2.x * DD + d0);
    const s16x8 v3 = *(const s16x8*)(H + (size_t)c3.x * DD + d0);
    const float w0 = __int_as_float(c0.y), w1 = __int_as_float(c1.y);
    const float w2 = __int_as_float(c2.y), w3 = __int_as_float(c3.y);
    #pragma unroll
    for (int j = 0; j < 8; ++j) {
      acc[j] += bf2f((u16)v0[j]) * w0;
      acc[j] += bf2f((u16)v1[j]) * w1;
      acc[j] += bf2f((u16)v2[j]) * w2;
      acc[j] += bf2f((u16)v3[j]) * w3;
    }
  }
  for (; e < end; ++e) {
    const int2 c = csr[e];
    const s16x8 v = *(const s16x8*)(H + (size_t)c.x * DD + d0);
    const float w = __int_as_float(c.y);
    #pragma unroll
    for (int j = 0; j < 8; ++j) acc[j] += bf2f((u16)v[j]) * w;
  }
  s16x8 o;
  #pragma unroll
  for (int j = 0; j < 8; ++j) {
    float r = acc[j] + bias[d0 + j];
    r = fmaxf(r, 0.f);                          // relu
    o[j] = (short)f2bf(r);
  }
  *(s16x8*)(out + (size_t)node * DD + d0) = o;
}

// ---------------- launch ----------------

extern "C" void kernel_launch(void* const* d_in, const int* in_sizes, int n_in,
                              void* d_out, int out_size, void* d_ws, size_t ws_size,
                              hipStream_t stream) {
  const float* x    = (const float*)d_in[0];
  const int*   ei   = (const int*)d_in[1];
  const float* W1   = (const float*)d_in[2];
  const float* b1   = (const float*)d_in[3];
  const float* W2   = (const float*)d_in[4];
  const float* b2   = (const float*)d_in[5];
  const float* Wout = (const float*)d_in[6];
  const float* bout = (const float*)d_in[7];
  float* out = (float*)d_out;
  (void)in_sizes; (void)n_in; (void)out_size; (void)ws_size;

  char* ws = (char*)d_ws;
  size_t off = 0;
  auto alloc = [&](size_t bytes) -> char* {
    char* p = ws + off;
    off = (off + bytes + 255) & ~(size_t)255;
    return p;
  };
  u16*   xb   = (u16*)alloc((size_t)MP * DD * 2);   // activations bf16 (pad rows unused-garbage)
  u16*   H    = (u16*)alloc((size_t)NN * DD * 2);   // GEMM output bf16
  u16*   W1T  = (u16*)alloc(512 * 512 * 2);
  u16*   W2T  = (u16*)alloc(512 * 512 * 2);
  u16*   WoT  = (u16*)alloc(256 * 512 * 2);
  int*   cnt  = (int*)alloc(NN * 4);
  float* dinv = (float*)alloc(NN * 4);
  int*   rowp = (int*)alloc((NN + 1) * 4);
  int*   cur  = (int*)alloc(NN * 4);
  int2*  csr  = (int2*)alloc((size_t)(EE + NN) * 8);
  int*   bsum = (int*)alloc(NSCAN * 4);
  int*   boff = (int*)alloc(NSCAN * 4);

  const int* srcp = ei;        // edge_index[0]
  const int* dstp = ei + EE;   // edge_index[1]

  setup_k<<<2756, 256, 0, stream>>>(cnt, W1, W1T, W2, W2T, Wout, WoT);
  count_k<<<(EE + 255) / 256, 256, 0, stream>>>(dstp, cnt);
  scan1_k<<<NSCAN, 256, 0, stream>>>(cnt, bsum);
  scan2_k<<<1, 256, 0, stream>>>(bsum, boff);
  scan3_k<<<NSCAN, 256, 0, stream>>>(cnt, boff, rowp, cur, dinv);

  // layer 1 (fused scatter): H = bf16(x) @ W1 ; xb = relu(agg(H) + b1)
  gemm1_k<<<SCB + G1TILES, 256, 0, stream>>>(x, W1T, H, srcp, dstp, dinv, cur, csr);
  aggregate_k<<<NN / 4, 256, 0, stream>>>(H, rowp, csr, b1, xb);
  // layer 2
  gemm_k<1><<<(MP / 128) * (512 / 128), 256, 0, stream>>>(xb, W2T, (void*)H, nullptr, NN, 512);
  aggregate_k<<<NN / 4, 256, 0, stream>>>(H, rowp, csr, b2, xb);
  // output layer
  gemm_k<0><<<(MP / 128) * (256 / 128), 256, 0, stream>>>(xb, WoT, (void*)out, bout, NN, 256);
}